// Round 8
// baseline (448.425 us; speedup 1.0000x reference)
//
#include <hip/hip_runtime.h>
#include <stdint.h>

typedef int v4i  __attribute__((ext_vector_type(4)));
typedef int v16i __attribute__((ext_vector_type(16)));

#define M_TOK 8192
#define N_OUT 4096
#define K_IN  4096

// -------------------------------------------------------------------------
// Pack both int32-carrier tensors into row-major int8 (one dispatch).
// Coalesced: lane reads one int4 (16B), writes one packed int (4B).
// -------------------------------------------------------------------------
__device__ __forceinline__ int pack4(int4 a) {
    return (a.x & 255) | ((a.y & 255) << 8) | ((a.z & 255) << 16) | ((a.w & 255) << 24);
}

__global__ __launch_bounds__(256) void pack_both(
    const int4* __restrict__ x, const int4* __restrict__ w,
    int* __restrict__ dA, int* __restrict__ dB, int n4x, int n4w)
{
    int i = blockIdx.x * blockDim.x + threadIdx.x;
    if (i < n4x) {
        dA[i] = pack4(x[i]);
    } else {
        int j = i - n4x;
        if (j < n4w) dB[j] = pack4(w[j]);
    }
}

// -------------------------------------------------------------------------
// i8 GEMM: C[M,N] = A[M,K].B[N,K]^T.
// R8 change vs R3: block 256x128, 4 waves (2x2), wave tile 128x64 =
// 4x2 of mfma_i32_32x32x32_i8. Fragment-read ratio 0.75 b128/MFMA
// (vs R3's 1.0) and staging bytes/output halved -> per-128x128-equivalent
// LDS demand 72KB vs R3's 96KB. 32 MFMA per barrier-pair (vs 16).
// Schedule: R3's verified single-buffer 2-barrier loop (every explicit
// prefetch variant R4-R7 regressed; occupancy/TLP is what wins here).
// History: R3 159.5us (LDS ~86% busy, MfmaUtil 40%); R4 169; R5 194;
//          R6 181; R7 174.6 (direct-B: vector-return path bound).
// -------------------------------------------------------------------------
__global__ __launch_bounds__(256) void gemm_i8_kernel(
    const char* __restrict__ A8,      // [M][K] int8 row-major
    const char* __restrict__ B8,      // [N][K] int8 row-major
    const float* __restrict__ scale_ptr,
    float* __restrict__ out)          // [M][N] float + 1 scalar at end
{
    __shared__ alignas(16) char lA[256 * 128];   // 32 KB
    __shared__ alignas(16) char lB[128 * 128];   // 16 KB

    const int tid  = threadIdx.x;
    const int wave = tid >> 6;
    const int lane = tid & 63;

    const int bm = blockIdx.y * 256;
    const int bn = blockIdx.x * 128;   // x over N: consecutive blocks share A-panel

    const int wm = (wave >> 1) * 128;  // wave M offset: 0 / 128
    const int wn = (wave & 1) * 64;    // wave N offset: 0 / 64

    v16i acc[4][2];
#pragma unroll
    for (int i = 0; i < 4; ++i)
#pragma unroll
        for (int j = 0; j < 2; ++j)
#pragma unroll
            for (int r = 0; r < 16; ++r)
                acc[i][j][r] = 0;

    // ---- staging geometry (R3-verified pattern): chunks of 8 rows x 128B,
    // one wave-instr each; source column granule XOR-swizzled by row&7.
    // A: 256 rows -> wave stages rows [64w, 64w+64) = 8 chunks.
    // B: 128 rows -> wave stages rows [32w, 32w+32) = 4 chunks.
    const int srow = lane >> 3;
    const int scol = ((lane & 7) ^ srow) << 4;

    const char* gA[8]; char* lAp[8];
#pragma unroll
    for (int q = 0; q < 8; ++q) {
        int row0 = wave * 64 + q * 8;
        gA[q]  = A8 + (size_t)(bm + row0 + srow) * K_IN + scol;
        lAp[q] = lA + row0 * 128;
    }
    const char* gB[4]; char* lBp[4];
#pragma unroll
    for (int q = 0; q < 4; ++q) {
        int row0 = wave * 32 + q * 8;
        gB[q]  = B8 + (size_t)(bn + row0 + srow) * K_IN + scol;
        lBp[q] = lB + row0 * 128;
    }

    // ---- fragment geometry (R3-verified): A[m=lane&31][k=(lane>>5)*16+j]
    const int fm  = lane & 31;
    const int fh  = lane >> 5;
    const int fsw = fm & 7;

#pragma unroll 1
    for (int k0 = 0; k0 < K_IN; k0 += 128) {
#pragma unroll
        for (int q = 0; q < 8; ++q)
            __builtin_amdgcn_global_load_lds(
                (const __attribute__((address_space(1))) void*)(gA[q] + k0),
                (__attribute__((address_space(3))) void*)lAp[q], 16, 0, 0);
#pragma unroll
        for (int q = 0; q < 4; ++q)
            __builtin_amdgcn_global_load_lds(
                (const __attribute__((address_space(1))) void*)(gB[q] + k0),
                (__attribute__((address_space(3))) void*)lBp[q], 16, 0, 0);

        __syncthreads();   // staging visible

#pragma unroll
        for (int kk = 0; kk < 4; ++kk) {
            const int goff = ((kk * 2 + fh) ^ fsw) << 4;
            v4i bf0 = *(const v4i*)(lB + (wn + fm) * 128 + goff);
            v4i bf1 = *(const v4i*)(lB + (wn + 32 + fm) * 128 + goff);
#pragma unroll
            for (int t = 0; t < 4; ++t) {
                v4i af = *(const v4i*)(lA + (wm + t * 32 + fm) * 128 + goff);
                acc[t][0] = __builtin_amdgcn_mfma_i32_32x32x32_i8(af, bf0, acc[t][0], 0, 0, 0);
                acc[t][1] = __builtin_amdgcn_mfma_i32_32x32x32_i8(af, bf1, acc[t][1], 0, 0, 0);
            }
        }

        __syncthreads();   // reads done before next staging overwrites
    }

    // ---- epilogue (verified): y = clip(rint(acc*scale), -128, 127)
    // 32x32 C/D: col = lane&31, row = (r&3) + 8*(r>>2) + 4*(lane>>5)
    const float s     = scale_ptr[0];
    const float scale = (s * 0.1f) / 0.1f;

#pragma unroll
    for (int ti = 0; ti < 4; ++ti) {
#pragma unroll
        for (int tj = 0; tj < 2; ++tj) {
#pragma unroll
            for (int r = 0; r < 16; ++r) {
                int row = bm + wm + ti * 32 + (r & 3) + 8 * (r >> 2) + 4 * fh;
                int col = bn + wn + tj * 32 + fm;
                float y = (float)acc[ti][tj][r] * scale;
                y = rintf(y);
                y = fminf(fmaxf(y, -128.0f), 127.0f);
                out[(size_t)row * N_OUT + col] = y;
            }
        }
    }

    if (bm == 0 && bn == 0 && tid == 0)
        out[(size_t)M_TOK * N_OUT] = 0.1f;
}

// -------------------------------------------------------------------------
extern "C" void kernel_launch(void* const* d_in, const int* in_sizes, int n_in,
                              void* d_out, int out_size, void* d_ws, size_t ws_size,
                              hipStream_t stream)
{
    const int*   x_q     = (const int*)d_in[0];
    const int*   w_q     = (const int*)d_in[1];
    const float* scale_x = (const float*)d_in[2];
    float* out = (float*)d_out;

    char* A8 = (char*)d_ws;                              // 32 MB
    char* B8 = (char*)d_ws + (size_t)M_TOK * K_IN;       // 16 MB

    const int n4x = (M_TOK * K_IN) / 4;
    const int n4w = (N_OUT * K_IN) / 4;

    pack_both<<<(n4x + n4w) / 256, 256, 0, stream>>>(
        (const int4*)x_q, (const int4*)w_q, (int*)A8, (int*)B8, n4x, n4w);

    dim3 grid(N_OUT / 128, M_TOK / 256);   // (32, 32) = 1024 blocks
    gemm_i8_kernel<<<grid, 256, 0, stream>>>(A8, B8, scale_x, out);
}